// Round 3
// baseline (280.253 us; speedup 1.0000x reference)
//
#include <hip/hip_runtime.h>
#include <stdint.h>

// GAT layer, B=8, N=2048, D=128, fp32 in/out.
// prep_wt: W -> W^T bf16 hi/lo (for fc B-fragments).
// fc:      h = (x*mask)@W via 3-term bf16-split MFMA -> hT bf16 [B][D][N],
//          e_l, e_r (fp32, from fp32 accumulators).
// attn:    flash attention, 4-way split-K across waves, MFMA bf16 PV,
//          LDS merge + residual + LayerNorm epilogue.

#define BB 8
#define NN 2048
#define DD 128
#define GAT_NEG_INF -10000.0f
#define LN_EPS 1e-5f

typedef __attribute__((ext_vector_type(8))) short short8;
typedef __attribute__((ext_vector_type(4))) float f32x4;

__device__ __forceinline__ unsigned pk_bf16(float a, float b) {
    unsigned ua = __float_as_uint(a); ua += 0x7FFFu + ((ua >> 16) & 1u);
    unsigned ub = __float_as_uint(b); ub += 0x7FFFu + ((ub >> 16) & 1u);
    return (ua >> 16) | (ub & 0xFFFF0000u);
}
__device__ __forceinline__ unsigned short bf16_rtn(float a) {
    unsigned ua = __float_as_uint(a);
    return (unsigned short)((ua + 0x7FFFu + ((ua >> 16) & 1u)) >> 16);
}

// ---------------------------------------------------------------------------
// prep_wt: grid 64 x 256. WThi/WTlo[n][k] = bf16 split of W[k][n].
// ---------------------------------------------------------------------------
__global__ void prep_wt(const float* __restrict__ W,
                        unsigned short* __restrict__ WThi,
                        unsigned short* __restrict__ WTlo)
{
    int idx = blockIdx.x * 256 + threadIdx.x;   // 0..16383, coalesced read
    int k = idx >> 7, n = idx & 127;
    float w = W[idx];
    unsigned short hi = bf16_rtn(w);
    float hif = __uint_as_float((unsigned)hi << 16);
    WThi[n * DD + k] = hi;
    WTlo[n * DD + k] = bf16_rtn(w - hif);
}

// ---------------------------------------------------------------------------
// fc: grid = BB*(NN/64) = 256 blocks (b = blk&7), block 256 = 4 waves.
// Wave w: rows i0 = it*64 + w*16 .. +15. Lane: col = lane&15, grp = lane>>4.
// A-frag (x, hi/lo in-register):  A[m=col][k=grp*8+u]
// B-frag (WT bf16, 16B loads):    B[k=grp*8+u][n=col]
// C/D: col = lane&15 (=d sub), row = grp*4+reg (=i sub).
// ---------------------------------------------------------------------------
__global__ __launch_bounds__(256) void fc_kernel(
    const float* __restrict__ x, const int* __restrict__ mask,
    const unsigned short* __restrict__ WThi, const unsigned short* __restrict__ WTlo,
    const float* __restrict__ a_l, const float* __restrict__ a_r,
    unsigned short* __restrict__ hT, float* __restrict__ el, float* __restrict__ er)
{
    const int t    = threadIdx.x;
    const int wv   = t >> 6;
    const int lane = t & 63;
    const int col  = lane & 15;
    const int grp  = lane >> 4;
    const int b    = blockIdx.x & 7;
    const int it   = blockIdx.x >> 3;      // 0..31
    const int i0   = it * 64 + wv * 16;

    const float* xrow = x + ((size_t)(b * NN + i0 + col)) * DD + grp * 8;
    const float  mm   = (float)mask[b * NN + i0 + col];

    f32x4 acc[8];
#pragma unroll
    for (int nb = 0; nb < 8; ++nb) acc[nb] = (f32x4)0.f;

    union AU { unsigned u[4]; short8 v; };
    union BU { int4 q; short8 v; };

#pragma unroll
    for (int ks = 0; ks < 4; ++ks) {
        float4 xa = *(const float4*)(xrow + ks * 32);
        float4 xb = *(const float4*)(xrow + ks * 32 + 4);
        float xv[8] = {xa.x, xa.y, xa.z, xa.w, xb.x, xb.y, xb.z, xb.w};
        unsigned short hi[8]; float lo[8];
#pragma unroll
        for (int u = 0; u < 8; ++u) {
            float v = xv[u] * mm;
            hi[u] = bf16_rtn(v);
            lo[u] = v - __uint_as_float((unsigned)hi[u] << 16);
        }
        AU Ahi, Alo;
#pragma unroll
        for (int j = 0; j < 4; ++j) {
            Ahi.u[j] = (unsigned)hi[2 * j] | ((unsigned)hi[2 * j + 1] << 16);
            Alo.u[j] = pk_bf16(lo[2 * j], lo[2 * j + 1]);
        }
#pragma unroll
        for (int nb = 0; nb < 8; ++nb) {
            BU Bhi, Blo;
            Bhi.q = *(const int4*)(WThi + (nb * 16 + col) * DD + ks * 32 + grp * 8);
            Blo.q = *(const int4*)(WTlo + (nb * 16 + col) * DD + ks * 32 + grp * 8);
            acc[nb] = __builtin_amdgcn_mfma_f32_16x16x32_bf16(Ahi.v, Bhi.v, acc[nb], 0, 0, 0);
            acc[nb] = __builtin_amdgcn_mfma_f32_16x16x32_bf16(Alo.v, Bhi.v, acc[nb], 0, 0, 0);
            acc[nb] = __builtin_amdgcn_mfma_f32_16x16x32_bf16(Ahi.v, Blo.v, acc[nb], 0, 0, 0);
        }
    }

    // ---- e_l / e_r from fp32 accumulators ----
    float sl[4] = {0.f, 0.f, 0.f, 0.f}, sr[4] = {0.f, 0.f, 0.f, 0.f};
#pragma unroll
    for (int nb = 0; nb < 8; ++nb) {
        float alv = a_l[nb * 16 + col];
        float arv = a_r[nb * 16 + col];
#pragma unroll
        for (int reg = 0; reg < 4; ++reg) {
            sl[reg] += acc[nb][reg] * alv;
            sr[reg] += acc[nb][reg] * arv;
        }
    }
#pragma unroll
    for (int off = 1; off < 16; off <<= 1)
#pragma unroll
        for (int reg = 0; reg < 4; ++reg) {
            sl[reg] += __shfl_xor(sl[reg], off, 64);
            sr[reg] += __shfl_xor(sr[reg], off, 64);
        }
    if (col == 0) {
#pragma unroll
        for (int reg = 0; reg < 4; ++reg) {
            el[b * NN + i0 + grp * 4 + reg] = sl[reg];
            er[b * NN + i0 + grp * 4 + reg] = sr[reg];
        }
    }

    // ---- hT bf16 store: hT[b][d = nb*16+col][i = i0+grp*4+reg] ----
#pragma unroll
    for (int nb = 0; nb < 8; ++nb) {
        unsigned p01 = pk_bf16(acc[nb][0], acc[nb][1]);
        unsigned p23 = pk_bf16(acc[nb][2], acc[nb][3]);
        *(uint2*)(hT + ((size_t)(b * DD + nb * 16 + col)) * NN + i0 + grp * 4) =
            make_uint2(p01, p23);
    }
}

// ---------------------------------------------------------------------------
// attn: grid = BB*(NN/16) = 1024 blocks (b = blk&7), block 256 = 4 waves.
// Wave wv handles j in [wv*512, wv*512+512), 8 tiles of 64, private online
// softmax. Merge via LDS, then each wave does LN epilogue for 4 rows.
// ---------------------------------------------------------------------------
__global__ __launch_bounds__(256, 4) void attn_kernel(
    const float* __restrict__ x, const int* __restrict__ adj,
    const int* __restrict__ mask, const unsigned short* __restrict__ hT,
    const float* __restrict__ el, const float* __restrict__ er,
    const float* __restrict__ gamma, const float* __restrict__ beta,
    float* __restrict__ outp)
{
    __shared__ __align__(16) float macc[4][16][132];   // 33.8 KB
    __shared__ float mls[4][16][2];

    const int t    = threadIdx.x;
    const int wv   = t >> 6;
    const int lane = t & 63;
    const int row  = lane & 15;
    const int grp  = lane >> 4;
    const int b    = blockIdx.x & 7;
    const int it   = blockIdx.x >> 3;    // 0..127
    const int i0   = it * 16;
    const int gi   = i0 + row;
    const int j0   = wv * 512;

    const float el_r = el[b * NN + gi];
    const int   mi   = mask[b * NN + gi];
    const int*  adj_row = adj + ((size_t)(b * NN + gi)) * NN + j0;
    const float* er_w = er + b * NN + j0;
    const int*   mk_w = mask + b * NN + j0;
    const unsigned short* hT_b = hT + (size_t)b * DD * NN;

    f32x4 acc[8];
#pragma unroll
    for (int nb = 0; nb < 8; ++nb) acc[nb] = (f32x4)0.f;
    float m_run = -3.0e38f, l_run = 0.f;

    int4 pa0, pa1, pa2, pa3;
    float4 pe0, pe1, pe2, pe3;
    int4 pq0, pq1, pq2, pq3;

    auto load_meta = [&](int jt) {
        const int jb = jt * 64 + grp * 8;
        pa0 = *(const int4*)(adj_row + jb);
        pa1 = *(const int4*)(adj_row + jb + 4);
        pa2 = *(const int4*)(adj_row + jb + 32);
        pa3 = *(const int4*)(adj_row + jb + 36);
        pe0 = *(const float4*)(er_w + jb);
        pe1 = *(const float4*)(er_w + jb + 4);
        pe2 = *(const float4*)(er_w + jb + 32);
        pe3 = *(const float4*)(er_w + jb + 36);
        pq0 = *(const int4*)(mk_w + jb);
        pq1 = *(const int4*)(mk_w + jb + 4);
        pq2 = *(const int4*)(mk_w + jb + 32);
        pq3 = *(const int4*)(mk_w + jb + 36);
    };
    load_meta(0);

    union BU { int4 q; short8 v; };
    union AU { unsigned u[4]; short8 v; };

#pragma unroll 1
    for (int jt = 0; jt < 8; ++jt) {
        int4 a0 = pa0, a1 = pa1, a2 = pa2, a3 = pa3;
        float4 e0 = pe0, e1 = pe1, e2 = pe2, e3 = pe3;
        int4 q0 = pq0, q1 = pq1, q2 = pq2, q3 = pq3;
        load_meta(jt < 7 ? jt + 1 : jt);

        // B-fragment loads (L2-hot hT)
        BU bf[16];
        {
            const int jb = j0 + jt * 64 + grp * 8;
#pragma unroll
            for (int s = 0; s < 2; ++s)
#pragma unroll
                for (int nb = 0; nb < 8; ++nb)
                    bf[s * 8 + nb].q = *(const int4*)(hT_b
                        + (size_t)(nb * 16 + row) * NN + jb + s * 32);
        }

        int   av[16] = {a0.x,a0.y,a0.z,a0.w, a1.x,a1.y,a1.z,a1.w,
                        a2.x,a2.y,a2.z,a2.w, a3.x,a3.y,a3.z,a3.w};
        int   qv[16] = {q0.x,q0.y,q0.z,q0.w, q1.x,q1.y,q1.z,q1.w,
                        q2.x,q2.y,q2.z,q2.w, q3.x,q3.y,q3.z,q3.w};
        float ev[16] = {e0.x,e0.y,e0.z,e0.w, e1.x,e1.y,e1.z,e1.w,
                        e2.x,e2.y,e2.z,e2.w, e3.x,e3.y,e3.z,e3.w};
        float ss[16];
        float tmax = -3.0e38f;
#pragma unroll
        for (int u = 0; u < 16; ++u) {
            float e = el_r + ev[u];
            e = fmaxf(e, 0.2f * e);                 // LeakyReLU
            bool ok = (av[u] & qv[u] & mi) != 0;
            ss[u] = ok ? e : GAT_NEG_INF;
            tmax = fmaxf(tmax, ss[u]);
        }
        tmax = fmaxf(tmax, __shfl_xor(tmax, 16, 64));
        tmax = fmaxf(tmax, __shfl_xor(tmax, 32, 64));
        float m_new = fmaxf(m_run, tmax);
        float al    = __expf(m_run - m_new);
        float p[16];
        float psum = 0.f;
#pragma unroll
        for (int u = 0; u < 16; ++u) {
            p[u] = __expf(ss[u] - m_new);
            psum += p[u];
        }
        psum += __shfl_xor(psum, 16, 64);
        psum += __shfl_xor(psum, 32, 64);
        l_run = l_run * al + psum;
        m_run = m_new;

        float alr[4];
#pragma unroll
        for (int reg = 0; reg < 4; ++reg) alr[reg] = __shfl(al, grp * 4 + reg, 64);
#pragma unroll
        for (int nb = 0; nb < 8; ++nb) {
            acc[nb][0] *= alr[0]; acc[nb][1] *= alr[1];
            acc[nb][2] *= alr[2]; acc[nb][3] *= alr[3];
        }

        AU A0, A1;
#pragma unroll
        for (int k = 0; k < 4; ++k) {
            A0.u[k] = pk_bf16(p[2 * k],     p[2 * k + 1]);
            A1.u[k] = pk_bf16(p[8 + 2 * k], p[8 + 2 * k + 1]);
        }
#pragma unroll
        for (int nb = 0; nb < 8; ++nb)
            acc[nb] = __builtin_amdgcn_mfma_f32_16x16x32_bf16(A0.v, bf[nb].v, acc[nb], 0, 0, 0);
#pragma unroll
        for (int nb = 0; nb < 8; ++nb)
            acc[nb] = __builtin_amdgcn_mfma_f32_16x16x32_bf16(A1.v, bf[8 + nb].v, acc[nb], 0, 0, 0);
    }

    // ---- write partials to LDS ----
    if (grp == 0) { mls[wv][row][0] = m_run; mls[wv][row][1] = l_run; }
#pragma unroll
    for (int nb = 0; nb < 8; ++nb)
#pragma unroll
        for (int reg = 0; reg < 4; ++reg)
            macc[wv][grp * 4 + reg][nb * 16 + row] = acc[nb][reg];
    __syncthreads();

    // ---- merge + residual + mask + LayerNorm; wave wv owns rows wv*4..+3 ----
    const float g0  = gamma[2 * lane], g1 = gamma[2 * lane + 1];
    const float be0 = beta[2 * lane],  be1 = beta[2 * lane + 1];
#pragma unroll
    for (int q = 0; q < 4; ++q) {
        const int r  = wv * 4 + q;
        const int gir = i0 + r;
        float m0 = mls[0][r][0], m1 = mls[1][r][0], m2 = mls[2][r][0], m3 = mls[3][r][0];
        float m_f = fmaxf(fmaxf(m0, m1), fmaxf(m2, m3));
        float sc0 = __expf(m0 - m_f), sc1 = __expf(m1 - m_f);
        float sc2 = __expf(m2 - m_f), sc3 = __expf(m3 - m_f);
        float l_f = mls[0][r][1] * sc0 + mls[1][r][1] * sc1
                  + mls[2][r][1] * sc2 + mls[3][r][1] * sc3;
        float inv = 1.0f / l_f;
        float2 v0 = *(const float2*)&macc[0][r][2 * lane];
        float2 v1 = *(const float2*)&macc[1][r][2 * lane];
        float2 v2 = *(const float2*)&macc[2][r][2 * lane];
        float2 v3 = *(const float2*)&macc[3][r][2 * lane];
        float ox = v0.x * sc0 + v1.x * sc1 + v2.x * sc2 + v3.x * sc3;
        float oy = v0.y * sc0 + v1.y * sc1 + v2.y * sc2 + v3.y * sc3;

        float mq = (float)mask[b * NN + gir];
        float2 xv = *(const float2*)(x + ((size_t)(b * NN + gir)) * DD + 2 * lane);
        float w0 = (ox * inv + xv.x) * mq;
        float w1 = (oy * inv + xv.y) * mq;

        float s1 = w0 + w1, s2 = w0 * w0 + w1 * w1;
#pragma unroll
        for (int off = 32; off; off >>= 1) {
            s1 += __shfl_xor(s1, off, 64);
            s2 += __shfl_xor(s2, off, 64);
        }
        float mu  = s1 * (1.0f / DD);
        float var = s2 * (1.0f / DD) - mu * mu;
        float rsd = rsqrtf(var + LN_EPS);
        *(float2*)(outp + ((size_t)(b * NN + gir)) * DD + 2 * lane) =
            make_float2((w0 - mu) * rsd * g0 + be0, (w1 - mu) * rsd * g1 + be1);
    }
}

// ---------------------------------------------------------------------------
extern "C" void kernel_launch(void* const* d_in, const int* in_sizes, int n_in,
                              void* d_out, int out_size, void* d_ws, size_t ws_size,
                              hipStream_t stream) {
    const float* x     = (const float*)d_in[0];
    const int*   adj   = (const int*)d_in[1];
    const int*   maskp = (const int*)d_in[2];
    const float* W     = (const float*)d_in[3];
    const float* a_l   = (const float*)d_in[4];
    const float* a_r   = (const float*)d_in[5];
    const float* gamma = (const float*)d_in[6];
    const float* beta  = (const float*)d_in[7];
    float*       outp  = (float*)d_out;

    // ws: hT bf16 [B*D*N] (4MB) | el,er f32 [B*N] | WThi,WTlo bf16 [128*128]
    unsigned short* hT = (unsigned short*)d_ws;
    float* el = (float*)(hT + (size_t)BB * DD * NN);
    float* er = el + (size_t)BB * NN;
    unsigned short* WThi = (unsigned short*)(er + (size_t)BB * NN);
    unsigned short* WTlo = WThi + DD * DD;

    prep_wt<<<64, 256, 0, stream>>>(W, WThi, WTlo);
    fc_kernel<<<BB * (NN / 64), 256, 0, stream>>>(x, maskp, WThi, WTlo,
                                                  a_l, a_r, hT, el, er);
    attn_kernel<<<BB * (NN / 16), 256, 0, stream>>>(x, adj, maskp, hT, el, er,
                                                    gamma, beta, outp);
}